// Round 13
// baseline (155.381 us; speedup 1.0000x reference)
//
#include <hip/hip_runtime.h>

// Shapes: B=1, N=4096, C=256, H=8, d=32.
// ws layout (ushort elems):
//   Q[2][8][4096][32]          @ 0         (Q pre-scaled by d^-0.5*log2e)
//   K[2][8][4096][32]          @ KOFF
//   Vt[2][8][32][4096]         @ VOFF      (key dim permuted per 32-block to
//                                           PV A-frag slot order)
//   WBF[24][8192]              @ WOFF      (W bf16, swizzled to B-frag order)
//   Lsum[2][8][4096] (fp32)    @ LOFF      (softmax denominators, atomically
//                                           accumulated; zeroed per launch)

typedef __attribute__((ext_vector_type(8))) short short8;
typedef __attribute__((ext_vector_type(4))) float float4v;
typedef __attribute__((ext_vector_type(4))) unsigned int uint4v;

#define NTOK 4096
#define CDIM 256
#define HEADS 8
#define DHEAD 32

#define QOFF 0
#define KOFF (2*HEADS*NTOK*DHEAD)
#define VOFF (2*(2*HEADS*NTOK*DHEAD))
#define WOFF (3*(2*HEADS*NTOK*DHEAD))
#define LOFF (WOFF + 24*8192)            // ushort offset; region used as fp32

__device__ inline unsigned short f2bf(float f) {
    union { float f; unsigned u; } v; v.f = f;
    unsigned r = v.u + 0x7FFFu + ((v.u >> 16) & 1u);   // RNE
    return (unsigned short)(r >> 16);
}

// ---------------------------------------------------------------------------
// Kernel 0: W fp32 -> bf16, swizzled so a B-fragment is one contiguous 16B
// load: WBF[o32*8192 + (kk*2+nhalf)*512 + (quad*16+l16)*8 + j]
// ---------------------------------------------------------------------------
__global__ __launch_bounds__(256) void wconv_kernel(
    const float* __restrict__ W, unsigned short* __restrict__ ws)
{
    int idx = blockIdx.x*256 + threadIdx.x;    // [0, 24576): (row, col-octet)
    int R = idx >> 5, oct = idx & 31;
    int C = oct * 8;
    const float4* p = reinterpret_cast<const float4*>(W + R*CDIM + C);
    float4 a = p[0], b = p[1];
    short8 f;
    f[0]=(short)f2bf(a.x); f[1]=(short)f2bf(a.y); f[2]=(short)f2bf(a.z); f[3]=(short)f2bf(a.w);
    f[4]=(short)f2bf(b.x); f[5]=(short)f2bf(b.y); f[6]=(short)f2bf(b.z); f[7]=(short)f2bf(b.w);
    int o32 = R >> 5, r = R & 31;
    int kk = C >> 5, quad = (C >> 3) & 3;
    int dst = o32*8192 + (kk*2 + (r>>4))*512 + (quad*16 + (r&15))*8;
    *reinterpret_cast<short8*>(ws + WOFF + dst) = f;
}

// ---------------------------------------------------------------------------
// Kernel 1: t = x @ W^T (bf16 MFMA) + LayerNorm over d=32 groups.
// No LDS/barriers. grid = 1024: (row-tile 0..127) x (o-eighth 0..7, 3 o32s).
// ---------------------------------------------------------------------------
__global__ __launch_bounds__(256) void qkv_ln_kernel(
    const float* __restrict__ before, const float* __restrict__ after,
    const float* __restrict__ gamma, const float* __restrict__ beta,
    unsigned short* __restrict__ ws)
{
    const int tid  = threadIdx.x;
    const int lane = tid & 63;
    const int w    = tid >> 6;
    const int quad = lane >> 4;
    const int l16  = lane & 15;
    const int rt   = blockIdx.x >> 3;
    const int oq   = blockIdx.x & 7;

    const int mrow_frag = rt*64 + w*16 + l16;
    const int inp_f = mrow_frag >> 12;
    const int n_f   = mrow_frag & 4095;
    const float* x = inp_f ? after : before;

    short8 afrag[8];
#pragma unroll
    for (int kk = 0; kk < 8; kk++) {
        const float4* p = reinterpret_cast<const float4*>(x + n_f*CDIM + kk*32 + quad*8);
        float4 a = p[0], b = p[1];
        short8 f;
        f[0]=(short)f2bf(a.x); f[1]=(short)f2bf(a.y); f[2]=(short)f2bf(a.z); f[3]=(short)f2bf(a.w);
        f[4]=(short)f2bf(b.x); f[5]=(short)f2bf(b.y); f[6]=(short)f2bf(b.z); f[7]=(short)f2bf(b.w);
        afrag[kk] = f;
    }

    const float g0  = gamma[l16], g1  = gamma[16+l16];
    const float be0 = beta[l16],  be1 = beta[16+l16];
    const float cscale = 0.17677669529663687f * 1.4426950408889634f; // d^-0.5*log2e

    const int mrow_out  = rt*64 + w*16 + quad*4;
    const int inp_o     = mrow_out >> 12;
    const int n_o_base  = mrow_out & 4095;

    const unsigned short* wbf = ws + WOFF;

    for (int o32 = oq*3; o32 < oq*3 + 3; o32++) {
        const unsigned short* wb = wbf + o32*8192 + lane*8;
        float4v acc0 = {0.f,0.f,0.f,0.f}, acc1 = {0.f,0.f,0.f,0.f};
#pragma unroll
        for (int kk = 0; kk < 8; kk++) {
            short8 b0 = *reinterpret_cast<const short8*>(wb + (kk*2    )*512);
            short8 b1 = *reinterpret_cast<const short8*>(wb + (kk*2 + 1)*512);
            acc0 = __builtin_amdgcn_mfma_f32_16x16x32_bf16(afrag[kk], b0, acc0, 0,0,0);
            acc1 = __builtin_amdgcn_mfma_f32_16x16x32_bf16(afrag[kk], b1, acc1, 0,0,0);
        }

        const int which = o32 >> 3;     // 0=q 1=k 2=v
        const int h     = o32 & 7;
        unsigned short* qk = ws + (which == 0 ? QOFF : KOFF) + ((inp_o*HEADS + h)*NTOK)*DHEAD;
        unsigned short* vt = ws + VOFF + ((inp_o*HEADS + h)*DHEAD)*NTOK;
        const float qs = (which == 0) ? cscale : 1.0f;

#pragma unroll
        for (int i = 0; i < 4; i++) {
            float sum = acc0[i] + acc1[i];
            float sq  = acc0[i]*acc0[i] + acc1[i]*acc1[i];
#pragma unroll
            for (int m = 1; m < 16; m <<= 1) {
                sum += __shfl_xor(sum, m);
                sq  += __shfl_xor(sq,  m);
            }
            float mu   = sum * (1.0f/32.0f);
            float var  = sq * (1.0f/32.0f) - mu*mu;
            float rstd = rsqrtf(var + 1e-5f);
            float v0 = ((acc0[i]-mu)*rstd*g0 + be0) * qs;
            float v1 = ((acc1[i]-mu)*rstd*g1 + be1) * qs;
            int n = n_o_base + i;
            if (which < 2) {
                qk[n*DHEAD + l16]      = f2bf(v0);
                qk[n*DHEAD + 16 + l16] = f2bf(v1);
            } else {
                // PV A-frag slot order within each 32-key block
                int kb = n >> 5, ki = n & 31;
                int slot = ((ki & 15) >> 2)*8 + (ki & 3) + ((ki >> 4) << 2);
                int kp2 = kb*32 + slot;
                vt[l16*NTOK + kp2]       = f2bf(v0);
                vt[(16+l16)*NTOK + kp2]  = f2bf(v1);
            }
        }
    }
}

// ---------------------------------------------------------------------------
// Kernel 2: cross attention. R8/R10 structure (register softmax via S^T=K·Q^T,
// l on the MFMA pipe, XCD-pinned (h,X)) with keys ALSO split across blocks
// (kho 0/1, 2048 keys each) -> grid 2048 = ~7 resident blocks/CU (occupancy
// play). Linear (max-free) softmax partials merge via atomicAdd into the
// zeroed out + Lsum arrays; norm_kernel divides afterwards.
// Block = 4 waves = (q-half) x (key-quarter khi); single-buffered V LDS.
// ---------------------------------------------------------------------------
__global__ __launch_bounds__(256, 4) void attn_kernel(
    const unsigned short* __restrict__ ws, float* __restrict__ out)
{
    __shared__ unsigned short vlds[2][32*136];   // per khi: 32 d x 128 k'

    // XCD-locality decode: 2048 blocks; xcd = b&7 pins 2 (h,X) combos.
    const int b    = blockIdx.x;
    const int xcd  = b & 7;
    const int i_   = b >> 3;                    // 0..255
    const int combo = xcd*2 + (i_ >> 7);        // 0..15
    const int h   = combo & 7;
    const int X   = combo >> 3;
    const int qb  = (i_ >> 1) & 63;             // 64 q-rows per block
    const int khо = i_ & 1;                     // key outer half (2048 keys)

    const int qinp = 1 - X, kvinp = X;
    const int tid  = threadIdx.x;
    const int lane = tid & 63;
    const int w    = tid >> 6;
    const int qh   = w & 1;                     // q-half
    const int khi  = w >> 1;                    // key inner half (1024 keys)
    const int quad = lane >> 4;
    const int l16  = lane & 15;

    const unsigned short* qbase = ws + QOFF + ((qinp*HEADS + h)*NTOK)*DHEAD;
    const unsigned short* kbase = ws + KOFF + ((kvinp*HEADS + h)*NTOK)*DHEAD;
    const unsigned short* vbase = ws + VOFF + ((kvinp*HEADS + h)*DHEAD)*NTOK;

    const int q0 = qb*64 + qh*32;
    const int k0 = khо*2048 + khi*1024;         // this wave's 1024-key strip
    // Q as B-operand: B[n=q=l16][k=d=quad*8+j]
    const short8 qf0 = *reinterpret_cast<const short8*>(qbase + (q0 + l16)*DHEAD      + quad*8);
    const short8 qf1 = *reinterpret_cast<const short8*>(qbase + (q0 + 16 + l16)*DHEAD + quad*8);

    // K as A-operand: A[m=key(within tile)=l16][k=d=quad*8+j]
    const unsigned short* kp   = kbase + (k0 + l16)*DHEAD + quad*8;
    const unsigned short* vsrc = vbase + k0;    // rows stride NTOK

    const short8 ones = {0x3F80,0x3F80,0x3F80,0x3F80,0x3F80,0x3F80,0x3F80,0x3F80};

    float4v O00 = {0,0,0,0}, O01 = {0,0,0,0}, O10 = {0,0,0,0}, O11 = {0,0,0,0};
    float4v L0  = {0,0,0,0}, L1  = {0,0,0,0};   // row-sum accumulators

    unsigned short* vh = vlds[khi];
    const int t2 = qh*64 + lane;                // 0..127 within the khi pair
    const int vr = t2 >> 4;                     // V d-row this thread stages
    const int vc = (t2 & 15)*8;                 // V col octet

    for (int j = 0; j < 8; j++) {
        __syncthreads();    // prior reads of vlds complete
        // stage vlds[khi]: 32 d-rows x 128 k' cols; 128 threads x 4 stores
#pragma unroll
        for (int r = 0; r < 4; r++) {
            short8 d = *reinterpret_cast<const short8*>(vsrc + (vr + 8*r)*NTOK + j*128 + vc);
            *reinterpret_cast<short8*>(vh + (vr + 8*r)*136 + vc) = d;
        }
        __syncthreads();

#pragma unroll
        for (int grp = 0; grp < 4; grp++) {     // 32-key groups
            short8 kf0 = *reinterpret_cast<const short8*>(kp + (j*128 + grp*32     )*DHEAD);
            short8 kf1 = *reinterpret_cast<const short8*>(kp + (j*128 + grp*32 + 16)*DHEAD);
            short8 v0  = *reinterpret_cast<const short8*>(vh + l16*136      + grp*32 + quad*8);
            short8 v1  = *reinterpret_cast<const short8*>(vh + (16+l16)*136 + grp*32 + quad*8);
#pragma unroll
            for (int s = 0; s < 2; s++) {
                const short8 qf = s ? qf1 : qf0;
                float4v z = {0,0,0,0};
                float4v S0 = __builtin_amdgcn_mfma_f32_16x16x32_bf16(kf0, qf, z, 0,0,0);
                float4v S1 = __builtin_amdgcn_mfma_f32_16x16x32_bf16(kf1, qf, z, 0,0,0);
                union { float f; unsigned u; } u0,u1,u2,u3,u4,u5,u6,u7;
                u0.f = __builtin_amdgcn_exp2f(S0[0]);
                u1.f = __builtin_amdgcn_exp2f(S0[1]);
                u2.f = __builtin_amdgcn_exp2f(S0[2]);
                u3.f = __builtin_amdgcn_exp2f(S0[3]);
                u4.f = __builtin_amdgcn_exp2f(S1[0]);
                u5.f = __builtin_amdgcn_exp2f(S1[1]);
                u6.f = __builtin_amdgcn_exp2f(S1[2]);
                u7.f = __builtin_amdgcn_exp2f(S1[3]);
                union { short8 s8; uint4v u4v; } pfr;    // truncation pack
                pfr.u4v[0] = __builtin_amdgcn_perm(u1.u, u0.u, 0x07060302u);
                pfr.u4v[1] = __builtin_amdgcn_perm(u3.u, u2.u, 0x07060302u);
                pfr.u4v[2] = __builtin_amdgcn_perm(u5.u, u4.u, 0x07060302u);
                pfr.u4v[3] = __builtin_amdgcn_perm(u7.u, u6.u, 0x07060302u);
                if (s == 0) {
                    O00 = __builtin_amdgcn_mfma_f32_16x16x32_bf16(pfr.s8, v0,   O00, 0,0,0);
                    O01 = __builtin_amdgcn_mfma_f32_16x16x32_bf16(pfr.s8, v1,   O01, 0,0,0);
                    L0  = __builtin_amdgcn_mfma_f32_16x16x32_bf16(pfr.s8, ones, L0,  0,0,0);
                } else {
                    O10 = __builtin_amdgcn_mfma_f32_16x16x32_bf16(pfr.s8, v0,   O10, 0,0,0);
                    O11 = __builtin_amdgcn_mfma_f32_16x16x32_bf16(pfr.s8, v1,   O11, 0,0,0);
                    L1  = __builtin_amdgcn_mfma_f32_16x16x32_bf16(pfr.s8, ones, L1,  0,0,0);
                }
            }
        }
    }

    __syncthreads();    // vlds reads done before aliasing as combine buffer

    // combine khi-halves through LDS: [qh][32 rows][34 floats] (col 32 = l)
    float* comb = reinterpret_cast<float*>(&vlds[0][0]) + qh*(32*34);
    if (khi == 1) {
#pragma unroll
        for (int s = 0; s < 2; s++)
#pragma unroll
            for (int i = 0; i < 4; i++) {
                int row = s*16 + quad*4 + i;
                comb[row*34 + l16]      = (s ? O10[i] : O00[i]);
                comb[row*34 + 16 + l16] = (s ? O11[i] : O01[i]);
                if (l16 == 0) comb[row*34 + 32] = (s ? L1[i] : L0[i]);
            }
    }
    __syncthreads();

    if (khi == 0) {
        float* ob = out + (size_t)X*NTOK*CDIM + h*DHEAD;
        float* lp = reinterpret_cast<float*>(const_cast<unsigned short*>(ws) + LOFF)
                    + (X*HEADS + h)*NTOK;
#pragma unroll
        for (int s = 0; s < 2; s++) {
#pragma unroll
            for (int i = 0; i < 4; i++) {
                int row = s*16 + quad*4 + i;
                float l = (s ? L1[i] : L0[i]) + comb[row*34 + 32];
                float a = (s ? O10[i] : O00[i]) + comb[row*34 + l16];
                float bb = (s ? O11[i] : O01[i]) + comb[row*34 + 16 + l16];
                int orow = q0 + row;
                atomicAdd(&ob[orow*CDIM + l16],      a);
                atomicAdd(&ob[orow*CDIM + 16 + l16], bb);
                if (l16 == 0) atomicAdd(&lp[orow], l);
            }
        }
    }
}

// ---------------------------------------------------------------------------
// Kernel 3: out[X][n][c] /= Lsum[X][c>>5][n]   (float4 per thread)
// ---------------------------------------------------------------------------
__global__ __launch_bounds__(256) void norm_kernel(
    float* __restrict__ out, const unsigned short* __restrict__ ws)
{
    const float* l = reinterpret_cast<const float*>(ws + LOFF);
    int idx = blockIdx.x*256 + threadIdx.x;     // 0..524287
    int o = idx * 4;
    int c = o & 255;
    int n = (o >> 8) & 4095;
    int X = o >> 20;
    float lv = l[(X*HEADS + (c >> 5))*NTOK + n];
    float inv = 1.0f / lv;
    float4* p = reinterpret_cast<float4*>(out) + idx;
    float4 v = *p;
    v.x *= inv; v.y *= inv; v.z *= inv; v.w *= inv;
    *p = v;
}

extern "C" void kernel_launch(void* const* d_in, const int* in_sizes, int n_in,
                              void* d_out, int out_size, void* d_ws, size_t ws_size,
                              hipStream_t stream)
{
    const float* before = (const float*)d_in[0];
    const float* after  = (const float*)d_in[1];
    const float* W      = (const float*)d_in[2];
    const float* gamma  = (const float*)d_in[3];
    const float* beta   = (const float*)d_in[4];
    float* out          = (float*)d_out;
    unsigned short* ws  = (unsigned short*)d_ws;   // needs ~13.3 MB

    // zero the atomic accumulation targets
    hipMemsetAsync(d_out, 0, (size_t)out_size * sizeof(float), stream);
    hipMemsetAsync(ws + LOFF, 0, (size_t)2*HEADS*NTOK*sizeof(float), stream);

    hipLaunchKernelGGL(wconv_kernel, dim3(96), dim3(256), 0, stream, W, ws);
    hipLaunchKernelGGL(qkv_ln_kernel, dim3(1024), dim3(256), 0, stream,
                       before, after, gamma, beta, ws);
    hipLaunchKernelGGL(attn_kernel, dim3(2048), dim3(256), 0, stream, ws, out);
    hipLaunchKernelGGL(norm_kernel, dim3(2048), dim3(256), 0, stream, out, ws);
}

// Round 14
// 140.221 us; speedup vs baseline: 1.1081x; 1.1081x over previous
//
#include <hip/hip_runtime.h>

// Shapes: B=1, N=4096, C=256, H=8, d=32.
// ws layout (ushort elems):
//   Q[2][8][4096][32]          @ 0         (Q pre-scaled by d^-0.5*log2e)
//   K[2][8][4096][32]          @ KOFF
//   Vb[2][8][128][2][512]      @ VOFF      (V in PV B-frag LINEAR order:
//                                           per 32-key block kb, per 16-d tile,
//                                           elem (d_lo, slot) at
//                                           ((slot>>3)*16+d_lo)*8 + (slot&7);
//                                           one B-frag = contiguous 1KB)
//   WBF[24][8192]              @ WOFF      (W bf16, swizzled to B-frag order)

typedef __attribute__((ext_vector_type(8))) short short8;
typedef __attribute__((ext_vector_type(4))) float float4v;
typedef __attribute__((ext_vector_type(4))) unsigned int uint4v;

#define NTOK 4096
#define CDIM 256
#define HEADS 8
#define DHEAD 32

#define QOFF 0
#define KOFF (2*HEADS*NTOK*DHEAD)
#define VOFF (2*(2*HEADS*NTOK*DHEAD))
#define WOFF (3*(2*HEADS*NTOK*DHEAD))

__device__ inline unsigned short f2bf(float f) {
    union { float f; unsigned u; } v; v.f = f;
    unsigned r = v.u + 0x7FFFu + ((v.u >> 16) & 1u);   // RNE
    return (unsigned short)(r >> 16);
}

// ---------------------------------------------------------------------------
// Kernel 0: W fp32 -> bf16, swizzled so a B-fragment is one contiguous 16B
// load: WBF[o32*8192 + (kk*2+nhalf)*512 + (quad*16+l16)*8 + j]
// ---------------------------------------------------------------------------
__global__ __launch_bounds__(256) void wconv_kernel(
    const float* __restrict__ W, unsigned short* __restrict__ ws)
{
    int idx = blockIdx.x*256 + threadIdx.x;    // [0, 24576): (row, col-octet)
    int R = idx >> 5, oct = idx & 31;
    int C = oct * 8;
    const float4* p = reinterpret_cast<const float4*>(W + R*CDIM + C);
    float4 a = p[0], b = p[1];
    short8 f;
    f[0]=(short)f2bf(a.x); f[1]=(short)f2bf(a.y); f[2]=(short)f2bf(a.z); f[3]=(short)f2bf(a.w);
    f[4]=(short)f2bf(b.x); f[5]=(short)f2bf(b.y); f[6]=(short)f2bf(b.z); f[7]=(short)f2bf(b.w);
    int o32 = R >> 5, r = R & 31;
    int kk = C >> 5, quad = (C >> 3) & 3;
    int dst = o32*8192 + (kk*2 + (r>>4))*512 + (quad*16 + (r&15))*8;
    *reinterpret_cast<short8*>(ws + WOFF + dst) = f;
}

// ---------------------------------------------------------------------------
// Kernel 1: t = x @ W^T (bf16 MFMA) + LayerNorm over d=32 groups.
// No LDS/barriers. grid = 1024: (row-tile 0..127) x (o-eighth 0..7, 3 o32s).
// ---------------------------------------------------------------------------
__global__ __launch_bounds__(256) void qkv_ln_kernel(
    const float* __restrict__ before, const float* __restrict__ after,
    const float* __restrict__ gamma, const float* __restrict__ beta,
    unsigned short* __restrict__ ws)
{
    const int tid  = threadIdx.x;
    const int lane = tid & 63;
    const int w    = tid >> 6;
    const int quad = lane >> 4;
    const int l16  = lane & 15;
    const int rt   = blockIdx.x >> 3;
    const int oq   = blockIdx.x & 7;

    const int mrow_frag = rt*64 + w*16 + l16;
    const int inp_f = mrow_frag >> 12;
    const int n_f   = mrow_frag & 4095;
    const float* x = inp_f ? after : before;

    short8 afrag[8];
#pragma unroll
    for (int kk = 0; kk < 8; kk++) {
        const float4* p = reinterpret_cast<const float4*>(x + n_f*CDIM + kk*32 + quad*8);
        float4 a = p[0], b = p[1];
        short8 f;
        f[0]=(short)f2bf(a.x); f[1]=(short)f2bf(a.y); f[2]=(short)f2bf(a.z); f[3]=(short)f2bf(a.w);
        f[4]=(short)f2bf(b.x); f[5]=(short)f2bf(b.y); f[6]=(short)f2bf(b.z); f[7]=(short)f2bf(b.w);
        afrag[kk] = f;
    }

    const float g0  = gamma[l16], g1  = gamma[16+l16];
    const float be0 = beta[l16],  be1 = beta[16+l16];
    const float cscale = 0.17677669529663687f * 1.4426950408889634f; // d^-0.5*log2e

    const int mrow_out  = rt*64 + w*16 + quad*4;
    const int inp_o     = mrow_out >> 12;
    const int n_o_base  = mrow_out & 4095;

    const unsigned short* wbf = ws + WOFF;

    for (int o32 = oq*3; o32 < oq*3 + 3; o32++) {
        const unsigned short* wb = wbf + o32*8192 + lane*8;
        float4v acc0 = {0.f,0.f,0.f,0.f}, acc1 = {0.f,0.f,0.f,0.f};
#pragma unroll
        for (int kk = 0; kk < 8; kk++) {
            short8 b0 = *reinterpret_cast<const short8*>(wb + (kk*2    )*512);
            short8 b1 = *reinterpret_cast<const short8*>(wb + (kk*2 + 1)*512);
            acc0 = __builtin_amdgcn_mfma_f32_16x16x32_bf16(afrag[kk], b0, acc0, 0,0,0);
            acc1 = __builtin_amdgcn_mfma_f32_16x16x32_bf16(afrag[kk], b1, acc1, 0,0,0);
        }

        const int which = o32 >> 3;     // 0=q 1=k 2=v
        const int h     = o32 & 7;
        unsigned short* qk = ws + (which == 0 ? QOFF : KOFF) + ((inp_o*HEADS + h)*NTOK)*DHEAD;
        unsigned short* vb = ws + VOFF + ((inp_o*HEADS + h)*128)*1024;
        const float qs = (which == 0) ? cscale : 1.0f;

#pragma unroll
        for (int i = 0; i < 4; i++) {
            float sum = acc0[i] + acc1[i];
            float sq  = acc0[i]*acc0[i] + acc1[i]*acc1[i];
#pragma unroll
            for (int m = 1; m < 16; m <<= 1) {
                sum += __shfl_xor(sum, m);
                sq  += __shfl_xor(sq,  m);
            }
            float mu   = sum * (1.0f/32.0f);
            float var  = sq * (1.0f/32.0f) - mu*mu;
            float rstd = rsqrtf(var + 1e-5f);
            float v0 = ((acc0[i]-mu)*rstd*g0 + be0) * qs;
            float v1 = ((acc1[i]-mu)*rstd*g1 + be1) * qs;
            int n = n_o_base + i;
            if (which < 2) {
                qk[n*DHEAD + l16]      = f2bf(v0);
                qk[n*DHEAD + 16 + l16] = f2bf(v1);
            } else {
                // B-frag linear layout: key n -> block kb, slot within block;
                // elem (d_lo, slot) at ((slot>>3)*16 + d_lo)*8 + (slot&7)
                int kb = n >> 5, ki = n & 31;
                int slot = ((ki & 15) >> 2)*8 + (ki & 3) + ((ki >> 4) << 2);
                int off  = ((slot >> 3)*16 + l16)*8 + (slot & 7);
                vb[kb*1024 + off]       = f2bf(v0);   // d = l16   (tile 0)
                vb[kb*1024 + 512 + off] = f2bf(v1);   // d = 16+l16 (tile 1)
            }
        }
    }
}

// ---------------------------------------------------------------------------
// Kernel 2: cross attention — BARRIER-FREE main loop, no LDS staging.
// S^T = K·Q^T lands as the PV A-fragment (register softmax, truncation pack);
// l rides the MFMA pipe (ones-B). K A-frags AND V B-frags are both fully
// coalesced 1KB global loads (V stored in B-frag-linear order), streaming
// from the XCD-pinned L2. Only sync: one barrier before the key-half combine.
// Block = 4 waves = (q-half) x (key-half); grid 1024 flat = 4 blocks/CU.
// ---------------------------------------------------------------------------
__global__ __launch_bounds__(256, 4) void attn_kernel(
    const unsigned short* __restrict__ ws, float* __restrict__ out)
{
    __shared__ float comb[2][32][34];           // [qh][row][d0..31, l]

    // XCD-locality decode: xcd = b&7 -> combo = xcd*2 + (i>>6), qb = i&63
    const int b    = blockIdx.x;
    const int xcd  = b & 7;
    const int i_   = b >> 3;                    // 0..127
    const int combo = xcd*2 + (i_ >> 6);        // 0..15
    const int h  = combo & 7;
    const int X  = combo >> 3;
    const int qb = i_ & 63;                     // 64 q-rows per block

    const int qinp = 1 - X, kvinp = X;
    const int tid  = threadIdx.x;
    const int lane = tid & 63;
    const int w    = tid >> 6;
    const int qh   = w & 1;                     // q-half
    const int kh   = w >> 1;                    // key-half
    const int quad = lane >> 4;
    const int l16  = lane & 15;

    const unsigned short* qbase = ws + QOFF + ((qinp*HEADS + h)*NTOK)*DHEAD;
    const unsigned short* kbase = ws + KOFF + ((kvinp*HEADS + h)*NTOK)*DHEAD;
    const unsigned short* vbase = ws + VOFF + ((kvinp*HEADS + h)*128)*1024;

    const int q0 = qb*64 + qh*32;
    // Q as B-operand: B[n=q=l16][k=d=quad*8+j]
    const short8 qf0 = *reinterpret_cast<const short8*>(qbase + (q0 + l16)*DHEAD      + quad*8);
    const short8 qf1 = *reinterpret_cast<const short8*>(qbase + (q0 + 16 + l16)*DHEAD + quad*8);

    // K as A-operand: A[m=key(within tile)=l16][k=d=quad*8+j] — coalesced 1KB
    const unsigned short* kp = kbase + (kh*2048 + l16)*DHEAD + quad*8;
    // V as B-operand: contiguous lane*8 within each 1KB tile — coalesced 1KB
    const unsigned short* vp = vbase + (kh*64)*1024 + lane*8;

    const short8 ones = {0x3F80,0x3F80,0x3F80,0x3F80,0x3F80,0x3F80,0x3F80,0x3F80};

    float4v O00 = {0,0,0,0}, O01 = {0,0,0,0}, O10 = {0,0,0,0}, O11 = {0,0,0,0};
    float4v L0  = {0,0,0,0}, L1  = {0,0,0,0};   // row-sum accumulators

    for (int j = 0; j < 16; j++) {
#pragma unroll
        for (int grp = 0; grp < 4; grp++) {     // 32-key groups
            const int ko = j*128 + grp*32;      // key offset in this half
            const int kb = j*4 + grp;           // 32-key block index
            short8 kf0 = *reinterpret_cast<const short8*>(kp + (ko     )*DHEAD);
            short8 kf1 = *reinterpret_cast<const short8*>(kp + (ko + 16)*DHEAD);
            short8 v0  = *reinterpret_cast<const short8*>(vp + kb*1024);
            short8 v1  = *reinterpret_cast<const short8*>(vp + kb*1024 + 512);
#pragma unroll
            for (int s = 0; s < 2; s++) {
                const short8 qf = s ? qf1 : qf0;
                float4v z = {0,0,0,0};
                float4v S0 = __builtin_amdgcn_mfma_f32_16x16x32_bf16(kf0, qf, z, 0,0,0);
                float4v S1 = __builtin_amdgcn_mfma_f32_16x16x32_bf16(kf1, qf, z, 0,0,0);
                union { float f; unsigned u; } u0,u1,u2,u3,u4,u5,u6,u7;
                u0.f = __builtin_amdgcn_exp2f(S0[0]);
                u1.f = __builtin_amdgcn_exp2f(S0[1]);
                u2.f = __builtin_amdgcn_exp2f(S0[2]);
                u3.f = __builtin_amdgcn_exp2f(S0[3]);
                u4.f = __builtin_amdgcn_exp2f(S1[0]);
                u5.f = __builtin_amdgcn_exp2f(S1[1]);
                u6.f = __builtin_amdgcn_exp2f(S1[2]);
                u7.f = __builtin_amdgcn_exp2f(S1[3]);
                union { short8 s8; uint4v u4v; } pfr;    // truncation pack
                pfr.u4v[0] = __builtin_amdgcn_perm(u1.u, u0.u, 0x07060302u);
                pfr.u4v[1] = __builtin_amdgcn_perm(u3.u, u2.u, 0x07060302u);
                pfr.u4v[2] = __builtin_amdgcn_perm(u5.u, u4.u, 0x07060302u);
                pfr.u4v[3] = __builtin_amdgcn_perm(u7.u, u6.u, 0x07060302u);
                if (s == 0) {
                    O00 = __builtin_amdgcn_mfma_f32_16x16x32_bf16(pfr.s8, v0,   O00, 0,0,0);
                    O01 = __builtin_amdgcn_mfma_f32_16x16x32_bf16(pfr.s8, v1,   O01, 0,0,0);
                    L0  = __builtin_amdgcn_mfma_f32_16x16x32_bf16(pfr.s8, ones, L0,  0,0,0);
                } else {
                    O10 = __builtin_amdgcn_mfma_f32_16x16x32_bf16(pfr.s8, v0,   O10, 0,0,0);
                    O11 = __builtin_amdgcn_mfma_f32_16x16x32_bf16(pfr.s8, v1,   O11, 0,0,0);
                    L1  = __builtin_amdgcn_mfma_f32_16x16x32_bf16(pfr.s8, ones, L1,  0,0,0);
                }
            }
        }
    }

    // combine key-halves: kh=1 publishes, one barrier, kh=0 merges + writes.
    // L accumulators: row = q (quad*4+i), all cols equal -> lane's L[i] is l.
    if (kh == 1) {
#pragma unroll
        for (int s = 0; s < 2; s++)
#pragma unroll
            for (int i = 0; i < 4; i++) {
                int row = s*16 + quad*4 + i;
                comb[qh][row][l16]      = (s ? O10[i] : O00[i]);
                comb[qh][row][16 + l16] = (s ? O11[i] : O01[i]);
                if (l16 == 0) comb[qh][row][32] = (s ? L1[i] : L0[i]);
            }
    }
    __syncthreads();

    if (kh == 0) {
        float* ob = out + (size_t)X*NTOK*CDIM + h*DHEAD;
#pragma unroll
        for (int s = 0; s < 2; s++) {
#pragma unroll
            for (int i = 0; i < 4; i++) {
                int row = s*16 + quad*4 + i;
                float l = (s ? L1[i] : L0[i]) + comb[qh][row][32];
                float inv = 1.0f / l;
                float a = ((s ? O10[i] : O00[i]) + comb[qh][row][l16])      * inv;
                float bb = ((s ? O11[i] : O01[i]) + comb[qh][row][16 + l16]) * inv;
                int orow = q0 + row;
                ob[orow*CDIM + l16]      = a;
                ob[orow*CDIM + 16 + l16] = bb;
            }
        }
    }
}

extern "C" void kernel_launch(void* const* d_in, const int* in_sizes, int n_in,
                              void* d_out, int out_size, void* d_ws, size_t ws_size,
                              hipStream_t stream)
{
    const float* before = (const float*)d_in[0];
    const float* after  = (const float*)d_in[1];
    const float* W      = (const float*)d_in[2];
    const float* gamma  = (const float*)d_in[3];
    const float* beta   = (const float*)d_in[4];
    float* out          = (float*)d_out;
    unsigned short* ws  = (unsigned short*)d_ws;   // needs ~13.0 MB

    hipLaunchKernelGGL(wconv_kernel, dim3(96), dim3(256), 0, stream, W, ws);
    hipLaunchKernelGGL(qkv_ln_kernel, dim3(1024), dim3(256), 0, stream,
                       before, after, gamma, beta, ws);
    hipLaunchKernelGGL(attn_kernel, dim3(1024), dim3(256), 0, stream, ws, out);
}

// Round 15
// 139.226 us; speedup vs baseline: 1.1160x; 1.0072x over previous
//
#include <hip/hip_runtime.h>

// Shapes: B=1, N=4096, C=256, H=8, d=32.
// ws layout (ushort elems):
//   Q[2][8][4096][32]          @ 0         (Q pre-scaled by d^-0.5*log2e)
//   K[2][8][4096][32]          @ KOFF
//   Vb[2][8][128][2][512]      @ VOFF      (V in PV B-frag LINEAR order:
//                                           per 32-key block kb, per 16-d tile,
//                                           elem (d_lo, slot) at
//                                           ((slot>>3)*16+d_lo)*8 + (slot&7))
//   WBF[24][8192]              @ WOFF      (W bf16, swizzled to B-frag order)

typedef __attribute__((ext_vector_type(8))) short short8;
typedef __attribute__((ext_vector_type(4))) float float4v;
typedef __attribute__((ext_vector_type(4))) unsigned int uint4v;

#define NTOK 4096
#define CDIM 256
#define HEADS 8
#define DHEAD 32

#define QOFF 0
#define KOFF (2*HEADS*NTOK*DHEAD)
#define VOFF (2*(2*HEADS*NTOK*DHEAD))
#define WOFF (3*(2*HEADS*NTOK*DHEAD))

__device__ inline unsigned short f2bf(float f) {
    union { float f; unsigned u; } v; v.f = f;
    unsigned r = v.u + 0x7FFFu + ((v.u >> 16) & 1u);   // RNE
    return (unsigned short)(r >> 16);
}

// exp2 + truncation-pack two S tiles (8 floats) into one PV A-fragment
__device__ inline short8 exp_pack(float4v S0, float4v S1) {
    union { float f; unsigned u; } u0,u1,u2,u3,u4,u5,u6,u7;
    u0.f = __builtin_amdgcn_exp2f(S0[0]);
    u1.f = __builtin_amdgcn_exp2f(S0[1]);
    u2.f = __builtin_amdgcn_exp2f(S0[2]);
    u3.f = __builtin_amdgcn_exp2f(S0[3]);
    u4.f = __builtin_amdgcn_exp2f(S1[0]);
    u5.f = __builtin_amdgcn_exp2f(S1[1]);
    u6.f = __builtin_amdgcn_exp2f(S1[2]);
    u7.f = __builtin_amdgcn_exp2f(S1[3]);
    union { short8 s8; uint4v u4v; } p;
    p.u4v[0] = __builtin_amdgcn_perm(u1.u, u0.u, 0x07060302u);
    p.u4v[1] = __builtin_amdgcn_perm(u3.u, u2.u, 0x07060302u);
    p.u4v[2] = __builtin_amdgcn_perm(u5.u, u4.u, 0x07060302u);
    p.u4v[3] = __builtin_amdgcn_perm(u7.u, u6.u, 0x07060302u);
    return p.s8;
}

// ---------------------------------------------------------------------------
// Kernel 0: W fp32 -> bf16, swizzled so a B-fragment is one contiguous 16B
// load: WBF[o32*8192 + (kk*2+nhalf)*512 + (quad*16+l16)*8 + j]
// ---------------------------------------------------------------------------
__global__ __launch_bounds__(256) void wconv_kernel(
    const float* __restrict__ W, unsigned short* __restrict__ ws)
{
    int idx = blockIdx.x*256 + threadIdx.x;    // [0, 24576): (row, col-octet)
    int R = idx >> 5, oct = idx & 31;
    int C = oct * 8;
    const float4* p = reinterpret_cast<const float4*>(W + R*CDIM + C);
    float4 a = p[0], b = p[1];
    short8 f;
    f[0]=(short)f2bf(a.x); f[1]=(short)f2bf(a.y); f[2]=(short)f2bf(a.z); f[3]=(short)f2bf(a.w);
    f[4]=(short)f2bf(b.x); f[5]=(short)f2bf(b.y); f[6]=(short)f2bf(b.z); f[7]=(short)f2bf(b.w);
    int o32 = R >> 5, r = R & 31;
    int kk = C >> 5, quad = (C >> 3) & 3;
    int dst = o32*8192 + (kk*2 + (r>>4))*512 + (quad*16 + (r&15))*8;
    *reinterpret_cast<short8*>(ws + WOFF + dst) = f;
}

// ---------------------------------------------------------------------------
// Kernel 1: t = x @ W^T (bf16 MFMA) + LayerNorm over d=32 groups.
// No LDS/barriers. grid = 1024: (row-tile 0..127) x (o-eighth 0..7, 3 o32s).
// ---------------------------------------------------------------------------
__global__ __launch_bounds__(256) void qkv_ln_kernel(
    const float* __restrict__ before, const float* __restrict__ after,
    const float* __restrict__ gamma, const float* __restrict__ beta,
    unsigned short* __restrict__ ws)
{
    const int tid  = threadIdx.x;
    const int lane = tid & 63;
    const int w    = tid >> 6;
    const int quad = lane >> 4;
    const int l16  = lane & 15;
    const int rt   = blockIdx.x >> 3;
    const int oq   = blockIdx.x & 7;

    const int mrow_frag = rt*64 + w*16 + l16;
    const int inp_f = mrow_frag >> 12;
    const int n_f   = mrow_frag & 4095;
    const float* x = inp_f ? after : before;

    short8 afrag[8];
#pragma unroll
    for (int kk = 0; kk < 8; kk++) {
        const float4* p = reinterpret_cast<const float4*>(x + n_f*CDIM + kk*32 + quad*8);
        float4 a = p[0], b = p[1];
        short8 f;
        f[0]=(short)f2bf(a.x); f[1]=(short)f2bf(a.y); f[2]=(short)f2bf(a.z); f[3]=(short)f2bf(a.w);
        f[4]=(short)f2bf(b.x); f[5]=(short)f2bf(b.y); f[6]=(short)f2bf(b.z); f[7]=(short)f2bf(b.w);
        afrag[kk] = f;
    }

    const float g0  = gamma[l16], g1  = gamma[16+l16];
    const float be0 = beta[l16],  be1 = beta[16+l16];
    const float cscale = 0.17677669529663687f * 1.4426950408889634f; // d^-0.5*log2e

    const int mrow_out  = rt*64 + w*16 + quad*4;
    const int inp_o     = mrow_out >> 12;
    const int n_o_base  = mrow_out & 4095;

    const unsigned short* wbf = ws + WOFF;

    for (int o32 = oq*3; o32 < oq*3 + 3; o32++) {
        const unsigned short* wb = wbf + o32*8192 + lane*8;
        float4v acc0 = {0.f,0.f,0.f,0.f}, acc1 = {0.f,0.f,0.f,0.f};
#pragma unroll
        for (int kk = 0; kk < 8; kk++) {
            short8 b0 = *reinterpret_cast<const short8*>(wb + (kk*2    )*512);
            short8 b1 = *reinterpret_cast<const short8*>(wb + (kk*2 + 1)*512);
            acc0 = __builtin_amdgcn_mfma_f32_16x16x32_bf16(afrag[kk], b0, acc0, 0,0,0);
            acc1 = __builtin_amdgcn_mfma_f32_16x16x32_bf16(afrag[kk], b1, acc1, 0,0,0);
        }

        const int which = o32 >> 3;     // 0=q 1=k 2=v
        const int h     = o32 & 7;
        unsigned short* qk = ws + (which == 0 ? QOFF : KOFF) + ((inp_o*HEADS + h)*NTOK)*DHEAD;
        unsigned short* vb = ws + VOFF + ((inp_o*HEADS + h)*128)*1024;
        const float qs = (which == 0) ? cscale : 1.0f;

#pragma unroll
        for (int i = 0; i < 4; i++) {
            float sum = acc0[i] + acc1[i];
            float sq  = acc0[i]*acc0[i] + acc1[i]*acc1[i];
#pragma unroll
            for (int m = 1; m < 16; m <<= 1) {
                sum += __shfl_xor(sum, m);
                sq  += __shfl_xor(sq,  m);
            }
            float mu   = sum * (1.0f/32.0f);
            float var  = sq * (1.0f/32.0f) - mu*mu;
            float rstd = rsqrtf(var + 1e-5f);
            float v0 = ((acc0[i]-mu)*rstd*g0 + be0) * qs;
            float v1 = ((acc1[i]-mu)*rstd*g1 + be1) * qs;
            int n = n_o_base + i;
            if (which < 2) {
                qk[n*DHEAD + l16]      = f2bf(v0);
                qk[n*DHEAD + 16 + l16] = f2bf(v1);
            } else {
                // B-frag linear layout: key n -> block kb, slot within block;
                // elem (d_lo, slot) at ((slot>>3)*16 + d_lo)*8 + (slot&7)
                int kb = n >> 5, ki = n & 31;
                int slot = ((ki & 15) >> 2)*8 + (ki & 3) + ((ki >> 4) << 2);
                int off  = ((slot >> 3)*16 + l16)*8 + (slot & 7);
                vb[kb*1024 + off]       = f2bf(v0);   // d = l16   (tile 0)
                vb[kb*1024 + 512 + off] = f2bf(v1);   // d = 16+l16 (tile 1)
            }
        }
    }
}

// ---------------------------------------------------------------------------
// Kernel 2: cross attention — barrier-free streaming + EXPLICIT 2-STAGE
// SOFTWARE PIPELINE over 64 chain-steps (32 keys each): iteration t issues
// t+1's K/V loads, runs s=0 exp/pack/PV of t (VALU), then t+1's four S-MFMAs
// (matrix pipe runs under s=1's VALU), then s=1 exp/pack/PV of t. Distinct
// S_cur/S_next registers force VALU/MFMA overlap the 48-VGPR schedule missed.
// Block = 4 waves = (q-half) x (key-half); grid 1024 flat, XCD-pinned (h,X).
// ---------------------------------------------------------------------------
__global__ __launch_bounds__(256, 4) void attn_kernel(
    const unsigned short* __restrict__ ws, float* __restrict__ out)
{
    __shared__ float comb[2][32][34];           // [qh][row][d0..31, l]

    // XCD-locality decode: xcd = b&7 -> combo = xcd*2 + (i>>6), qb = i&63
    const int b    = blockIdx.x;
    const int xcd  = b & 7;
    const int i_   = b >> 3;                    // 0..127
    const int combo = xcd*2 + (i_ >> 6);        // 0..15
    const int h  = combo & 7;
    const int X  = combo >> 3;
    const int qb = i_ & 63;                     // 64 q-rows per block

    const int qinp = 1 - X, kvinp = X;
    const int tid  = threadIdx.x;
    const int lane = tid & 63;
    const int w    = tid >> 6;
    const int qh   = w & 1;                     // q-half
    const int kh   = w >> 1;                    // key-half
    const int quad = lane >> 4;
    const int l16  = lane & 15;

    const unsigned short* qbase = ws + QOFF + ((qinp*HEADS + h)*NTOK)*DHEAD;
    const unsigned short* kbase = ws + KOFF + ((kvinp*HEADS + h)*NTOK)*DHEAD;
    const unsigned short* vbase = ws + VOFF + ((kvinp*HEADS + h)*128)*1024;

    const int q0 = qb*64 + qh*32;
    // Q as B-operand: B[n=q=l16][k=d=quad*8+j]
    const short8 qf0 = *reinterpret_cast<const short8*>(qbase + (q0 + l16)*DHEAD      + quad*8);
    const short8 qf1 = *reinterpret_cast<const short8*>(qbase + (q0 + 16 + l16)*DHEAD + quad*8);

    // K as A-operand (coalesced 1KB); V as B-operand (B-frag-linear, 1KB)
    const unsigned short* kp = kbase + (kh*2048 + l16)*DHEAD + quad*8;
    const unsigned short* vp = vbase + (kh*64)*1024 + lane*8;

    const short8 ones = {0x3F80,0x3F80,0x3F80,0x3F80,0x3F80,0x3F80,0x3F80,0x3F80};

    float4v O00 = {0,0,0,0}, O01 = {0,0,0,0}, O10 = {0,0,0,0}, O11 = {0,0,0,0};
    float4v L0  = {0,0,0,0}, L1  = {0,0,0,0};   // row-sum accumulators
    const float4v z = {0,0,0,0};

    // ---- pipeline prologue: step 0 loads + S ----
    short8 cv0 = *reinterpret_cast<const short8*>(vp);
    short8 cv1 = *reinterpret_cast<const short8*>(vp + 512);
    float4v Sc0, Sc1, Sc2, Sc3;
    {
        short8 kf0 = *reinterpret_cast<const short8*>(kp);
        short8 kf1 = *reinterpret_cast<const short8*>(kp + 16*DHEAD);
        Sc0 = __builtin_amdgcn_mfma_f32_16x16x32_bf16(kf0, qf0, z, 0,0,0);
        Sc1 = __builtin_amdgcn_mfma_f32_16x16x32_bf16(kf1, qf0, z, 0,0,0);
        Sc2 = __builtin_amdgcn_mfma_f32_16x16x32_bf16(kf0, qf1, z, 0,0,0);
        Sc3 = __builtin_amdgcn_mfma_f32_16x16x32_bf16(kf1, qf1, z, 0,0,0);
    }

    for (int t = 0; t < 64; t++) {
        const int tn = (t + 1) & 63;            // branch-free wrap (t=63 redundant)
        // (1) issue next step's loads — in flight under the VALU below
        short8 nkf0 = *reinterpret_cast<const short8*>(kp + (tn*32     )*DHEAD);
        short8 nkf1 = *reinterpret_cast<const short8*>(kp + (tn*32 + 16)*DHEAD);
        short8 nv0  = *reinterpret_cast<const short8*>(vp + tn*1024);
        short8 nv1  = *reinterpret_cast<const short8*>(vp + tn*1024 + 512);

        // (2) s=0 of step t: VALU exp/pack, then PV on matrix pipe
        {
            short8 pf = exp_pack(Sc0, Sc1);
            O00 = __builtin_amdgcn_mfma_f32_16x16x32_bf16(pf, cv0,  O00, 0,0,0);
            O01 = __builtin_amdgcn_mfma_f32_16x16x32_bf16(pf, cv1,  O01, 0,0,0);
            L0  = __builtin_amdgcn_mfma_f32_16x16x32_bf16(pf, ones, L0,  0,0,0);
        }

        // (3) step t+1's S-MFMAs — matrix pipe busy under (4)'s VALU
        float4v Sn0 = __builtin_amdgcn_mfma_f32_16x16x32_bf16(nkf0, qf0, z, 0,0,0);
        float4v Sn1 = __builtin_amdgcn_mfma_f32_16x16x32_bf16(nkf1, qf0, z, 0,0,0);
        float4v Sn2 = __builtin_amdgcn_mfma_f32_16x16x32_bf16(nkf0, qf1, z, 0,0,0);
        float4v Sn3 = __builtin_amdgcn_mfma_f32_16x16x32_bf16(nkf1, qf1, z, 0,0,0);

        // (4) s=1 of step t
        {
            short8 pf = exp_pack(Sc2, Sc3);
            O10 = __builtin_amdgcn_mfma_f32_16x16x32_bf16(pf, cv0,  O10, 0,0,0);
            O11 = __builtin_amdgcn_mfma_f32_16x16x32_bf16(pf, cv1,  O11, 0,0,0);
            L1  = __builtin_amdgcn_mfma_f32_16x16x32_bf16(pf, ones, L1,  0,0,0);
        }

        // (5) rotate pipeline state
        Sc0 = Sn0; Sc1 = Sn1; Sc2 = Sn2; Sc3 = Sn3;
        cv0 = nv0; cv1 = nv1;
    }

    // combine key-halves: kh=1 publishes, one barrier, kh=0 merges + writes.
    // L accumulators: row = q (quad*4+i), all cols equal -> lane's L[i] is l.
    if (kh == 1) {
#pragma unroll
        for (int s = 0; s < 2; s++)
#pragma unroll
            for (int i = 0; i < 4; i++) {
                int row = s*16 + quad*4 + i;
                comb[qh][row][l16]      = (s ? O10[i] : O00[i]);
                comb[qh][row][16 + l16] = (s ? O11[i] : O01[i]);
                if (l16 == 0) comb[qh][row][32] = (s ? L1[i] : L0[i]);
            }
    }
    __syncthreads();

    if (kh == 0) {
        float* ob = out + (size_t)X*NTOK*CDIM + h*DHEAD;
#pragma unroll
        for (int s = 0; s < 2; s++) {
#pragma unroll
            for (int i = 0; i < 4; i++) {
                int row = s*16 + quad*4 + i;
                float l = (s ? L1[i] : L0[i]) + comb[qh][row][32];
                float inv = 1.0f / l;
                float a  = ((s ? O10[i] : O00[i]) + comb[qh][row][l16])      * inv;
                float bb = ((s ? O11[i] : O01[i]) + comb[qh][row][16 + l16]) * inv;
                int orow = q0 + row;
                ob[orow*CDIM + l16]      = a;
                ob[orow*CDIM + 16 + l16] = bb;
            }
        }
    }
}

extern "C" void kernel_launch(void* const* d_in, const int* in_sizes, int n_in,
                              void* d_out, int out_size, void* d_ws, size_t ws_size,
                              hipStream_t stream)
{
    const float* before = (const float*)d_in[0];
    const float* after  = (const float*)d_in[1];
    const float* W      = (const float*)d_in[2];
    const float* gamma  = (const float*)d_in[3];
    const float* beta   = (const float*)d_in[4];
    float* out          = (float*)d_out;
    unsigned short* ws  = (unsigned short*)d_ws;   // needs ~13.0 MB

    hipLaunchKernelGGL(wconv_kernel, dim3(96), dim3(256), 0, stream, W, ws);
    hipLaunchKernelGGL(qkv_ln_kernel, dim3(1024), dim3(256), 0, stream,
                       before, after, gamma, beta, ws);
    hipLaunchKernelGGL(attn_kernel, dim3(1024), dim3(256), 0, stream, ws, out);
}

// Round 17
// 137.569 us; speedup vs baseline: 1.1295x; 1.0120x over previous
//
#include <hip/hip_runtime.h>

// Shapes: B=1, N=4096, C=256, H=8, d=32.
// ws layout (ushort elems):
//   Q[2][8][4096][32]          @ 0         (Q pre-scaled by d^-0.5*log2e)
//   K[2][8][4096][32]          @ KOFF
//   Vb[2][8][128][2][512]      @ VOFF      (V in PV B-frag LINEAR order:
//                                           per 32-key block kb, per 16-d tile,
//                                           elem (d_lo, slot) at
//                                           ((slot>>3)*16+d_lo)*8 + (slot&7))
//   WBF[24][8192]              @ WOFF      (W bf16, swizzled to B-frag order)

typedef __attribute__((ext_vector_type(8))) short short8;
typedef __attribute__((ext_vector_type(4))) float float4v;
typedef __attribute__((ext_vector_type(4))) unsigned int uint4v;

#define NTOK 4096
#define CDIM 256
#define HEADS 8
#define DHEAD 32

#define QOFF 0
#define KOFF (2*HEADS*NTOK*DHEAD)
#define VOFF (2*(2*HEADS*NTOK*DHEAD))
#define WOFF (3*(2*HEADS*NTOK*DHEAD))

__device__ inline unsigned short f2bf(float f) {
    union { float f; unsigned u; } v; v.f = f;
    unsigned r = v.u + 0x7FFFu + ((v.u >> 16) & 1u);   // RNE
    return (unsigned short)(r >> 16);
}

// exp2 + truncation-pack two S tiles (8 floats) into one PV A-fragment
__device__ inline short8 exp_pack(float4v S0, float4v S1) {
    union { float f; unsigned u; } u0,u1,u2,u3,u4,u5,u6,u7;
    u0.f = __builtin_amdgcn_exp2f(S0[0]);
    u1.f = __builtin_amdgcn_exp2f(S0[1]);
    u2.f = __builtin_amdgcn_exp2f(S0[2]);
    u3.f = __builtin_amdgcn_exp2f(S0[3]);
    u4.f = __builtin_amdgcn_exp2f(S1[0]);
    u5.f = __builtin_amdgcn_exp2f(S1[1]);
    u6.f = __builtin_amdgcn_exp2f(S1[2]);
    u7.f = __builtin_amdgcn_exp2f(S1[3]);
    union { short8 s8; uint4v u4v; } p;
    p.u4v[0] = __builtin_amdgcn_perm(u1.u, u0.u, 0x07060302u);
    p.u4v[1] = __builtin_amdgcn_perm(u3.u, u2.u, 0x07060302u);
    p.u4v[2] = __builtin_amdgcn_perm(u5.u, u4.u, 0x07060302u);
    p.u4v[3] = __builtin_amdgcn_perm(u7.u, u6.u, 0x07060302u);
    return p.s8;
}

// ---------------------------------------------------------------------------
// Kernel 0: W fp32 -> bf16, swizzled so a B-fragment is one contiguous 16B
// load: WBF[o32*8192 + (kk*2+nhalf)*512 + (quad*16+l16)*8 + j]
// ---------------------------------------------------------------------------
__global__ __launch_bounds__(256) void wconv_kernel(
    const float* __restrict__ W, unsigned short* __restrict__ ws)
{
    int idx = blockIdx.x*256 + threadIdx.x;    // [0, 24576): (row, col-octet)
    int R = idx >> 5, oct = idx & 31;
    int C = oct * 8;
    const float4* p = reinterpret_cast<const float4*>(W + R*CDIM + C);
    float4 a = p[0], b = p[1];
    short8 f;
    f[0]=(short)f2bf(a.x); f[1]=(short)f2bf(a.y); f[2]=(short)f2bf(a.z); f[3]=(short)f2bf(a.w);
    f[4]=(short)f2bf(b.x); f[5]=(short)f2bf(b.y); f[6]=(short)f2bf(b.z); f[7]=(short)f2bf(b.w);
    int o32 = R >> 5, r = R & 31;
    int kk = C >> 5, quad = (C >> 3) & 3;
    int dst = o32*8192 + (kk*2 + (r>>4))*512 + (quad*16 + (r&15))*8;
    *reinterpret_cast<short8*>(ws + WOFF + dst) = f;
}

// ---------------------------------------------------------------------------
// Kernel 1: t = x @ W^T (bf16 MFMA) + LayerNorm over d=32 groups.
// No LDS/barriers. grid = 1024: (row-tile 0..127) x (o-eighth 0..7, 3 o32s).
// ---------------------------------------------------------------------------
__global__ __launch_bounds__(256) void qkv_ln_kernel(
    const float* __restrict__ before, const float* __restrict__ after,
    const float* __restrict__ gamma, const float* __restrict__ beta,
    unsigned short* __restrict__ ws)
{
    const int tid  = threadIdx.x;
    const int lane = tid & 63;
    const int w    = tid >> 6;
    const int quad = lane >> 4;
    const int l16  = lane & 15;
    const int rt   = blockIdx.x >> 3;
    const int oq   = blockIdx.x & 7;

    const int mrow_frag = rt*64 + w*16 + l16;
    const int inp_f = mrow_frag >> 12;
    const int n_f   = mrow_frag & 4095;
    const float* x = inp_f ? after : before;

    short8 afrag[8];
#pragma unroll
    for (int kk = 0; kk < 8; kk++) {
        const float4* p = reinterpret_cast<const float4*>(x + n_f*CDIM + kk*32 + quad*8);
        float4 a = p[0], b = p[1];
        short8 f;
        f[0]=(short)f2bf(a.x); f[1]=(short)f2bf(a.y); f[2]=(short)f2bf(a.z); f[3]=(short)f2bf(a.w);
        f[4]=(short)f2bf(b.x); f[5]=(short)f2bf(b.y); f[6]=(short)f2bf(b.z); f[7]=(short)f2bf(b.w);
        afrag[kk] = f;
    }

    const float g0  = gamma[l16], g1  = gamma[16+l16];
    const float be0 = beta[l16],  be1 = beta[16+l16];
    const float cscale = 0.17677669529663687f * 1.4426950408889634f; // d^-0.5*log2e

    const int mrow_out  = rt*64 + w*16 + quad*4;
    const int inp_o     = mrow_out >> 12;
    const int n_o_base  = mrow_out & 4095;

    const unsigned short* wbf = ws + WOFF;

    for (int o32 = oq*3; o32 < oq*3 + 3; o32++) {
        const unsigned short* wb = wbf + o32*8192 + lane*8;
        float4v acc0 = {0.f,0.f,0.f,0.f}, acc1 = {0.f,0.f,0.f,0.f};
#pragma unroll
        for (int kk = 0; kk < 8; kk++) {
            short8 b0 = *reinterpret_cast<const short8*>(wb + (kk*2    )*512);
            short8 b1 = *reinterpret_cast<const short8*>(wb + (kk*2 + 1)*512);
            acc0 = __builtin_amdgcn_mfma_f32_16x16x32_bf16(afrag[kk], b0, acc0, 0,0,0);
            acc1 = __builtin_amdgcn_mfma_f32_16x16x32_bf16(afrag[kk], b1, acc1, 0,0,0);
        }

        const int which = o32 >> 3;     // 0=q 1=k 2=v
        const int h     = o32 & 7;
        unsigned short* qk = ws + (which == 0 ? QOFF : KOFF) + ((inp_o*HEADS + h)*NTOK)*DHEAD;
        unsigned short* vb = ws + VOFF + ((inp_o*HEADS + h)*128)*1024;
        const float qs = (which == 0) ? cscale : 1.0f;

#pragma unroll
        for (int i = 0; i < 4; i++) {
            float sum = acc0[i] + acc1[i];
            float sq  = acc0[i]*acc0[i] + acc1[i]*acc1[i];
#pragma unroll
            for (int m = 1; m < 16; m <<= 1) {
                sum += __shfl_xor(sum, m);
                sq  += __shfl_xor(sq,  m);
            }
            float mu   = sum * (1.0f/32.0f);
            float var  = sq * (1.0f/32.0f) - mu*mu;
            float rstd = rsqrtf(var + 1e-5f);
            float v0 = ((acc0[i]-mu)*rstd*g0 + be0) * qs;
            float v1 = ((acc1[i]-mu)*rstd*g1 + be1) * qs;
            int n = n_o_base + i;
            if (which < 2) {
                qk[n*DHEAD + l16]      = f2bf(v0);
                qk[n*DHEAD + 16 + l16] = f2bf(v1);
            } else {
                // B-frag linear layout: key n -> block kb, slot within block;
                // elem (d_lo, slot) at ((slot>>3)*16 + d_lo)*8 + (slot&7)
                int kb = n >> 5, ki = n & 31;
                int slot = ((ki & 15) >> 2)*8 + (ki & 3) + ((ki >> 4) << 2);
                int off  = ((slot >> 3)*16 + l16)*8 + (slot & 7);
                vb[kb*1024 + off]       = f2bf(v0);   // d = l16   (tile 0)
                vb[kb*1024 + 512 + off] = f2bf(v1);   // d = 16+l16 (tile 1)
            }
        }
    }
}

// ---------------------------------------------------------------------------
// Kernel 2: cross attention — barrier-free streaming, ZERO intra-block load
// duplication: block = 4 waves = 4 KEY-QUARTERS (1024 keys each), each wave
// computes ALL 64 q-rows (4 Q-frags). Each K/V load now feeds 64 q instead
// of 32 -> per-CU L1-return traffic halves (the R15 plateau's co-limiter).
// S^T = K·Q^T lands as the PV A-fragment (register softmax, truncation pack,
// exact O/l cancellation); l rides the MFMA pipe (ones-B). The 4 qi-chains
// per step give natural VALU/MFMA overlap. One barrier: 4-way merge in LDS.
// grid 1024 flat, XCD-pinned (h,X).
// ---------------------------------------------------------------------------
__global__ __launch_bounds__(256, 4) void attn_kernel(
    const unsigned short* __restrict__ ws, float* __restrict__ out)
{
    __shared__ float comb[3][64][33];           // waves 1..3: [row][d0..31, l]

    // XCD-locality decode: xcd = b&7 -> combo = xcd*2 + (i>>6), qb = i&63
    const int b    = blockIdx.x;
    const int xcd  = b & 7;
    const int i_   = b >> 3;                    // 0..127
    const int combo = xcd*2 + (i_ >> 6);        // 0..15
    const int h  = combo & 7;
    const int X  = combo >> 3;
    const int qb = i_ & 63;                     // 64 q-rows per block

    const int qinp = 1 - X, kvinp = X;
    const int tid  = threadIdx.x;
    const int lane = tid & 63;
    const int w    = tid >> 6;                  // key-quarter 0..3
    const int quad = lane >> 4;
    const int l16  = lane & 15;

    const unsigned short* qbase = ws + QOFF + ((qinp*HEADS + h)*NTOK)*DHEAD;
    const unsigned short* kbase = ws + KOFF + ((kvinp*HEADS + h)*NTOK)*DHEAD;
    const unsigned short* vbase = ws + VOFF + ((kvinp*HEADS + h)*128)*1024;

    const int q0 = qb*64;
    // Q as B-operand: B[n=q=l16][k=d=quad*8+j] — 4 fragments cover 64 q
    short8 qf[4];
#pragma unroll
    for (int qi = 0; qi < 4; qi++)
        qf[qi] = *reinterpret_cast<const short8*>(qbase + (q0 + qi*16 + l16)*DHEAD + quad*8);

    // K as A-operand (coalesced 1KB); V as B-operand (B-frag-linear, 1KB/blk)
    const unsigned short* kp = kbase + (w*1024 + l16)*DHEAD + quad*8;
    const unsigned short* vp = vbase + (w*32)*1024 + lane*8;

    const short8 ones = {0x3F80,0x3F80,0x3F80,0x3F80,0x3F80,0x3F80,0x3F80,0x3F80};

    float4v O[4][2], L[4];
#pragma unroll
    for (int qi = 0; qi < 4; qi++) {
        O[qi][0] = (float4v){0,0,0,0};
        O[qi][1] = (float4v){0,0,0,0};
        L[qi]    = (float4v){0,0,0,0};
    }
    const float4v z = {0,0,0,0};

    for (int t = 0; t < 32; t++) {              // 32-key steps over the quarter
        short8 kf0 = *reinterpret_cast<const short8*>(kp + (t*32     )*DHEAD);
        short8 kf1 = *reinterpret_cast<const short8*>(kp + (t*32 + 16)*DHEAD);
        short8 v0  = *reinterpret_cast<const short8*>(vp + t*1024);
        short8 v1  = *reinterpret_cast<const short8*>(vp + t*1024 + 512);
#pragma unroll
        for (int qi = 0; qi < 4; qi++) {        // 4 independent chains
            float4v S0 = __builtin_amdgcn_mfma_f32_16x16x32_bf16(kf0, qf[qi], z, 0,0,0);
            float4v S1 = __builtin_amdgcn_mfma_f32_16x16x32_bf16(kf1, qf[qi], z, 0,0,0);
            short8 pf = exp_pack(S0, S1);
            O[qi][0] = __builtin_amdgcn_mfma_f32_16x16x32_bf16(pf, v0,   O[qi][0], 0,0,0);
            O[qi][1] = __builtin_amdgcn_mfma_f32_16x16x32_bf16(pf, v1,   O[qi][1], 0,0,0);
            L[qi]    = __builtin_amdgcn_mfma_f32_16x16x32_bf16(pf, ones, L[qi],    0,0,0);
        }
    }

    // merge the 4 key-quarters: waves 1..3 publish, wave 0 merges + writes.
    // L: row = q (quad*4+i within the qi tile), all cols equal.
    if (w > 0) {
#pragma unroll
        for (int qi = 0; qi < 4; qi++)
#pragma unroll
            for (int i = 0; i < 4; i++) {
                int row = qi*16 + quad*4 + i;
                comb[w-1][row][l16]      = O[qi][0][i];
                comb[w-1][row][16 + l16] = O[qi][1][i];
                if (l16 == 0) comb[w-1][row][32] = L[qi][i];
            }
    }
    __syncthreads();

    if (w == 0) {
        float* ob = out + (size_t)X*NTOK*CDIM + h*DHEAD;
#pragma unroll
        for (int qi = 0; qi < 4; qi++) {
#pragma unroll
            for (int i = 0; i < 4; i++) {
                int row = qi*16 + quad*4 + i;
                float l  = L[qi][i]    + comb[0][row][32]      + comb[1][row][32]      + comb[2][row][32];
                float a  = O[qi][0][i] + comb[0][row][l16]     + comb[1][row][l16]     + comb[2][row][l16];
                float bb = O[qi][1][i] + comb[0][row][16+l16]  + comb[1][row][16+l16]  + comb[2][row][16+l16];
                float inv = 1.0f / l;
                int orow = q0 + row;
                ob[orow*CDIM + l16]      = a  * inv;
                ob[orow*CDIM + 16 + l16] = bb * inv;
            }
        }
    }
}

extern "C" void kernel_launch(void* const* d_in, const int* in_sizes, int n_in,
                              void* d_out, int out_size, void* d_ws, size_t ws_size,
                              hipStream_t stream)
{
    const float* before = (const float*)d_in[0];
    const float* after  = (const float*)d_in[1];
    const float* W      = (const float*)d_in[2];
    const float* gamma  = (const float*)d_in[3];
    const float* beta   = (const float*)d_in[4];
    float* out          = (float*)d_out;
    unsigned short* ws  = (unsigned short*)d_ws;   // needs ~13.0 MB

    hipLaunchKernelGGL(wconv_kernel, dim3(96), dim3(256), 0, stream, W, ws);
    hipLaunchKernelGGL(qkv_ln_kernel, dim3(1024), dim3(256), 0, stream,
                       before, after, gamma, beta, ws);
    hipLaunchKernelGGL(attn_kernel, dim3(1024), dim3(256), 0, stream, ws, out);
}